// Round 5
// baseline (54.895 us; speedup 1.0000x reference)
//
#include <hip/hip_runtime.h>

// Problem constants (match reference)
#define BATCH 256
#define PTS   4096
#define HH    512
#define WW    512

#define ROWS_PER_TILE 8
#define TILES (HH / ROWS_PER_TILE)       // 64 tiles per batch
#define TILE_ELEMS (ROWS_PER_TILE * WW)  // 4096 floats = 16 KB LDS

// Native vector type: __builtin_nontemporal_store requires an
// integer/float/vector-of-such pointer, not HIP's float4 class.
typedef float f32x4 __attribute__((ext_vector_type(4)));

// Tile-gather: each block owns one 8x512 output tile of one batch.
// 16 KB LDS -> 8 blocks/CU resident (wave-limited), so store bursts from
// some blocks hide scan/zero phases of others. Output written exactly
// once, non-temporal; no memset, no global atomics.
// HBM traffic ~= 268 MB write + ~15 MB read; scan redundancy (64x/batch)
// is absorbed by the per-XCD L2 via the batch->XCD remap.
__global__ __launch_bounds__(256) void tile_gather_kernel(
        const int* __restrict__ indices,      // [B, P, 2] int32
        const int* __restrict__ num_valid,    // [B] int32
        const float* __restrict__ feats,      // [B, P, 1] f32
        float* __restrict__ out)              // [B, H, W] f32
{
    __shared__ float tile[TILE_ELEMS];

    // XCD-aware remap: hardware round-robins blockIdx across the 8 XCDs.
    // Give each XCD 32 whole batches (all 64 tiles of each): the batch's
    // 32 KB index list + 16 KB feats stay in ONE L2.
    int i = blockIdx.x;                       // [0, 16384)
    int xcd  = i & 7;
    int slot = i >> 3;                        // [0, 2048)
    int b = xcd * (BATCH / 8) + (slot >> 6);  // 32 batches per XCD
    int t = slot & (TILES - 1);
    int r0 = t * ROWS_PER_TILE;
    int tidx = threadIdx.x;

    // Zero the LDS tile, vectorized (ds_write_b128): 4 stores/thread.
    f32x4* tile4 = reinterpret_cast<f32x4*>(tile);
    #pragma unroll
    for (int k = tidx; k < TILE_ELEMS / 4; k += 256)
        tile4[k] = (f32x4){0.f, 0.f, 0.f, 0.f};

    int nv = num_valid[b];                    // block-uniform
    __syncthreads();

    // Scan the valid prefix: 2 points per int4 load + one float2 feats
    // load (adjacent points' features are contiguous). L2-resident.
    const int4*   idx4 = reinterpret_cast<const int4*>(indices) + (size_t)b * (PTS / 2);
    const float2* fb2  = reinterpret_cast<const float2*>(feats) + (size_t)b * (PTS / 2);

    int n4 = (nv + 1) >> 1;                   // pairs to visit
    for (int q = tidx; q < n4; q += 256) {
        int4 two = idx4[q];                   // points 2q (x,y), 2q+1 (z,w)
        float2 v = fb2[q];
        int ra = two.x - r0;
        if ((unsigned)ra < ROWS_PER_TILE)
            atomicAdd(&tile[ra * WW + two.y], v.x);
        int rb = two.z - r0;
        if ((2 * q + 1) < nv && (unsigned)rb < ROWS_PER_TILE)
            atomicAdd(&tile[rb * WW + two.w], v.y);
    }
    __syncthreads();

    // Write the tile exactly once: 1024 float4 stores, 4 per thread,
    // non-temporal (output never re-read).
    float* ob = out + (size_t)b * (HH * WW) + (size_t)r0 * WW;
    f32x4* dst = reinterpret_cast<f32x4*>(ob);
    #pragma unroll
    for (int k = tidx; k < TILE_ELEMS / 4; k += 256)
        __builtin_nontemporal_store(tile4[k], dst + k);
}

extern "C" void kernel_launch(void* const* d_in, const int* in_sizes, int n_in,
                              void* d_out, int out_size, void* d_ws, size_t ws_size,
                              hipStream_t stream) {
    const int*   indices   = (const int*)d_in[0];
    const int*   num_valid = (const int*)d_in[1];
    const float* feats     = (const float*)d_in[2];
    float*       out       = (float*)d_out;

    tile_gather_kernel<<<BATCH * TILES, 256, 0, stream>>>(indices, num_valid, feats, out);
}